// Round 16
// baseline (6304.364 us; speedup 1.0000x reference)
//
#include <hip/hip_runtime.h>

namespace {
constexpr int kNT = 200000;
constexpr int kNM = 20000;
constexpr int kE  = 1000000;

// --- CSR build ---------------------------------------------------------------

__global__ void hist_kernel(const int4* __restrict__ tm4,
                            const int4* __restrict__ mt4,
                            int* __restrict__ cnt_m, int* __restrict__ cnt_t) {
  int stride = gridDim.x * blockDim.x;
  for (int i = blockIdx.x * blockDim.x + threadIdx.x; i < kE / 4; i += stride) {
    const int4 a = tm4[i];
    atomicAdd(&cnt_m[a.x], 1);
    atomicAdd(&cnt_m[a.y], 1);
    atomicAdd(&cnt_m[a.z], 1);
    atomicAdd(&cnt_m[a.w], 1);
    const int4 b = mt4[i];
    atomicAdd(&cnt_t[b.x], 1);
    atomicAdd(&cnt_t[b.y], 1);
    atomicAdd(&cnt_t[b.z], 1);
    atomicAdd(&cnt_t[b.w], 1);
  }
}

// Merged per-block exclusive scan (m blocks first, then t). Safe in-place.
__global__ __launch_bounds__(256) void scan_blocks_kernel(
    int* __restrict__ cm, int* __restrict__ ct, int* __restrict__ part_m,
    int* __restrict__ part_t, int nbm) {
  const bool is_m = (int)blockIdx.x < nbm;
  int* data = is_m ? cm : ct;
  int* partials = is_m ? part_m : part_t;
  const int b = is_m ? blockIdx.x : blockIdx.x - nbm;
  const int n = is_m ? kNM : kNT;
  __shared__ int lds[256];
  const int t = threadIdx.x;
  const int base = b * 1024;
  int v[4];
  int s = 0;
#pragma unroll
  for (int k = 0; k < 4; ++k) {
    int idx = base + t * 4 + k;
    v[k] = (idx < n) ? data[idx] : 0;
    s += v[k];
  }
  int x = s;
  lds[t] = x;
  __syncthreads();
  for (int off = 1; off < 256; off <<= 1) {
    int y = (t >= off) ? lds[t - off] : 0;
    __syncthreads();
    x += y;
    lds[t] = x;
    __syncthreads();
  }
  if (t == 255) partials[b] = x;
  int run = x - s;
#pragma unroll
  for (int k = 0; k < 4; ++k) {
    int idx = base + t * 4 + k;
    if (idx < n) data[idx] = run;
    run += v[k];
  }
}

// Grid=2: block 0 scans part_m (nbm entries), block 1 part_t (nbt). In-place
// inclusive->exclusive scan.
__global__ __launch_bounds__(256) void scan_partials_kernel(
    int* __restrict__ part_m, int* __restrict__ part_t, int nbm, int nbt) {
  int* p = (blockIdx.x == 0) ? part_m : part_t;
  const int nb = (blockIdx.x == 0) ? nbm : nbt;
  __shared__ int lds[256];
  const int t = threadIdx.x;
  int v = (t < nb) ? p[t] : 0;
  int x = v;
  lds[t] = x;
  __syncthreads();
  for (int off = 1; off < 256; off <<= 1) {
    int y = (t >= off) ? lds[t - off] : 0;
    __syncthreads();
    x += y;
    lds[t] = x;
    __syncthreads();
  }
  if (t < nb) p[t] = x - v;
}

__global__ void add_offsets_kernel(const int* __restrict__ cm,
                                   const int* __restrict__ ct,
                                   const int* __restrict__ pm,
                                   const int* __restrict__ pt,
                                   int* __restrict__ rp_m, int* __restrict__ rp_t,
                                   int* __restrict__ next_m,
                                   int* __restrict__ next_t) {
  int i = blockIdx.x * 256 + threadIdx.x;
  if (i == 0) {
    rp_m[kNM] = kE;
    rp_t[kNT] = kE;
  }
  if (i < kNM) {
    int v = cm[i] + pm[i >> 10];
    rp_m[i] = v;
    next_m[i] = v;
  } else if (i < kNM + kNT) {
    int j = i - kNM;
    int v = ct[j] + pt[j >> 10];
    rp_t[j] = v;
    next_t[j] = v;
  }
}

__global__ void fill_csr_kernel(const int4* __restrict__ tms4,
                                const int4* __restrict__ tmd4,
                                const int4* __restrict__ mts4,
                                const int4* __restrict__ mtd4,
                                int* __restrict__ next_m,
                                int* __restrict__ next_t,
                                int* __restrict__ csr_tm,
                                int* __restrict__ csr_mt) {
  int stride = gridDim.x * blockDim.x;
  for (int i = blockIdx.x * blockDim.x + threadIdx.x; i < kE / 4; i += stride) {
    const int4 s = tms4[i];
    const int4 d = tmd4[i];
    csr_tm[atomicAdd(&next_m[d.x], 1)] = s.x;
    csr_tm[atomicAdd(&next_m[d.y], 1)] = s.y;
    csr_tm[atomicAdd(&next_m[d.z], 1)] = s.z;
    csr_tm[atomicAdd(&next_m[d.w], 1)] = s.w;
    const int4 s2 = mts4[i];
    const int4 d2 = mtd4[i];
    csr_mt[atomicAdd(&next_t[d2.x], 1)] = s2.x;
    csr_mt[atomicAdd(&next_t[d2.y], 1)] = s2.y;
    csr_mt[atomicAdd(&next_t[d2.z], 1)] = s2.z;
    csr_mt[atomicAdd(&next_t[d2.w], 1)] = s2.w;
  }
}

// --- Fused SAGE layer --------------------------------------------------------
// 512 threads = 8 waves; each wave processes 4 nodes per iteration.
// Weights staged in LDS as packed bf16 pairs (2 k-values per dword) -> the
// weight LDS read is shared by 4 nodes' FMAs. Mean+self parked per node in a
// per-wave LDS row (same-wave ds ordering, no barrier); FMA loop reads them as
// broadcast b128 (conflict-free) and weights at 2-way alias (free).

__device__ inline unsigned bf16pack(float a, float b) {
  unsigned ua = __float_as_uint(a), ub = __float_as_uint(b);
  ua = (ua + 0x7FFFu + ((ua >> 16) & 1u)) >> 16;
  ub = (ub + 0x7FFFu + ((ub >> 16) & 1u)) >> 16;
  return (ua & 0xFFFFu) | (ub << 16);
}

template <int KL, int KR, bool HEAD>
__global__ __launch_bounds__(512) void fused_sage_kernel(
    const float* __restrict__ x_src, const float* __restrict__ x_self,
    const int* __restrict__ rp, const int* __restrict__ csr,
    const float* __restrict__ Wl, const float* __restrict__ bl,
    const float* __restrict__ Wr, float* __restrict__ hout, int n,
    const float* __restrict__ Wout, const float* __restrict__ bout,
    float* __restrict__ head_out) {
  constexpr int K = KL + KR;
  __shared__ unsigned sWp[(K / 2) * 64];  // packed bf16 pairs: [k/2][64]
  __shared__ float sZ[32][K];             // [wave*4+nb][mean(KL);self(KR)]
  const int t = threadIdx.x;
  for (int i = t; i < (K / 2) * 64; i += 512) {
    const int k2 = i >> 6, j = i & 63;
    const int k0 = k2 * 2, k1 = k0 + 1;
    const float w0 = (k0 < KL) ? Wl[k0 * 64 + j] : Wr[(k0 - KL) * 64 + j];
    const float w1 = (k1 < KL) ? Wl[k1 * 64 + j] : Wr[(k1 - KL) * 64 + j];
    sWp[i] = bf16pack(w0, w1);
  }
  __syncthreads();
  const int lane = t & 63;
  const int w = t >> 6;
  constexpr int F4 = KL / 4;      // float4s per source row
  constexpr int SLOTS = 64 / F4;  // rows gathered in parallel
  const int f4 = lane & (F4 - 1);
  const int slot = lane / F4;
  const float blj = bl[lane];
  const int zr = w * 4;
  for (int nb0 = (blockIdx.x * 8 + w) * 4; nb0 < n; nb0 += gridDim.x * 32) {
    // Gather + park 4 nodes (independent -> deep MLP).
#pragma unroll
    for (int nb = 0; nb < 4; ++nb) {
      const int node = nb0 + nb;
      if (node < n) {
        const int beg = rp[node], end = rp[node + 1];
        float ax = 0.f, ay = 0.f, az = 0.f, aw = 0.f;
        for (int base = beg; base < end; base += 4 * SLOTS) {
#pragma unroll
          for (int u = 0; u < 4; ++u) {
            const int e = base + u * SLOTS + slot;
            if (e < end) {
              const float4 v =
                  ((const float4*)(x_src + (long long)csr[e] * KL))[f4];
              ax += v.x;
              ay += v.y;
              az += v.z;
              aw += v.w;
            }
          }
        }
#pragma unroll
        for (int off = F4; off < 64; off <<= 1) {
          ax += __shfl_xor(ax, off, 64);
          ay += __shfl_xor(ay, off, 64);
          az += __shfl_xor(az, off, 64);
          aw += __shfl_xor(aw, off, 64);
        }
        const float r = 1.0f / fmaxf((float)(end - beg), 1.0f);
        if (lane < F4)
          ((float4*)sZ[zr + nb])[f4] = make_float4(ax * r, ay * r, az * r, aw * r);
        sZ[zr + nb][KL + lane] = x_self[(long long)node * KR + lane];
        if (KR == 128)
          sZ[zr + nb][KL + 64 + lane] = x_self[(long long)node * KR + 64 + lane];
      }
    }
    // Combined FMA for the 4 nodes (weight reads shared).
    float a0 = blj, a1 = blj, a2 = blj, a3 = blj;
    const float4* __restrict__ z0 = (const float4*)sZ[zr + 0];
    const float4* __restrict__ z1 = (const float4*)sZ[zr + 1];
    const float4* __restrict__ z2 = (const float4*)sZ[zr + 2];
    const float4* __restrict__ z3 = (const float4*)sZ[zr + 3];
#pragma unroll
    for (int k4 = 0; k4 < K / 4; ++k4) {
      const float4 m0 = z0[k4], m1 = z1[k4], m2 = z2[k4], m3 = z3[k4];
      const unsigned wp0 = sWp[(k4 * 2 + 0) * 64 + lane];
      const unsigned wp1 = sWp[(k4 * 2 + 1) * 64 + lane];
      const float w0 = __uint_as_float(wp0 << 16);
      const float w1 = __uint_as_float(wp0 & 0xFFFF0000u);
      const float w2 = __uint_as_float(wp1 << 16);
      const float w3 = __uint_as_float(wp1 & 0xFFFF0000u);
      a0 += m0.x * w0 + m0.y * w1 + m0.z * w2 + m0.w * w3;
      a1 += m1.x * w0 + m1.y * w1 + m1.z * w2 + m1.w * w3;
      a2 += m2.x * w0 + m2.y * w1 + m2.z * w2 + m2.w * w3;
      a3 += m3.x * w0 + m3.y * w1 + m3.z * w2 + m3.w * w3;
    }
#pragma unroll
    for (int nb = 0; nb < 4; ++nb) {
      const int node = nb0 + nb;
      if (node >= n) continue;
      const float acc = (nb == 0) ? a0 : (nb == 1) ? a1 : (nb == 2) ? a2 : a3;
      const float h = acc >= 0.f ? acc : 0.01f * acc;
      hout[(long long)node * 64 + lane] = h;
      if (HEAD) {
        float s0 = h * Wout[lane * 2 + 0];
        float s1 = h * Wout[lane * 2 + 1];
#pragma unroll
        for (int off = 32; off > 0; off >>= 1) {
          s0 += __shfl_xor(s0, off, 64);
          s1 += __shfl_xor(s1, off, 64);
        }
        if (lane == 0) {
          head_out[(long long)node * 2 + 0] = s0 + bout[0];
          head_out[(long long)node * 2 + 1] = s1 + bout[1];
        }
      }
    }
  }
}
}  // namespace

extern "C" void kernel_launch(void* const* d_in, const int* in_sizes, int n_in,
                              void* d_out, int out_size, void* d_ws, size_t ws_size,
                              hipStream_t stream) {
  const float* x_trans = (const float*)d_in[0];
  const float* x_merch = (const float*)d_in[1];
  const int* tm_src = (const int*)d_in[2];
  const int* tm_dst = (const int*)d_in[3];
  const int* mt_src = (const int*)d_in[4];
  const int* mt_dst = (const int*)d_in[5];
  const float* Wl_tm1 = (const float*)d_in[6];
  const float* bl_tm1 = (const float*)d_in[7];
  const float* Wr_tm1 = (const float*)d_in[8];
  const float* Wl_mt1 = (const float*)d_in[9];
  const float* bl_mt1 = (const float*)d_in[10];
  const float* Wr_mt1 = (const float*)d_in[11];
  // d_in[12..14]: layer-2 tm weights unused (h_m2 is dead in the reference).
  const float* Wl_mt2 = (const float*)d_in[15];
  const float* bl_mt2 = (const float*)d_in[16];
  const float* Wr_mt2 = (const float*)d_in[17];
  const float* W_out = (const float*)d_in[18];
  const float* b_out = (const float*)d_in[19];

  float* out_head = (float*)d_out;                   // [N_T, 2]
  float* h_t = (float*)d_out + (long long)kNT * 2;   // [N_T, 64]; layer-1 h_t,
                                                     // overwritten in-place with h_t2

  char* ws = (char*)d_ws;
  size_t off = 0;
  auto alloc = [&](size_t bytes) {
    char* p = ws + off;
    off = (off + bytes + 255) & ~(size_t)255;
    return p;
  };
  int* cnt_m = (int*)alloc(kNM * 4);  // scanned in place
  int* cnt_t = (int*)alloc(kNT * 4);
  int* rp_m = (int*)alloc((kNM + 1) * 4);
  int* rp_t = (int*)alloc((kNT + 1) * 4);
  int* next_m = (int*)alloc(kNM * 4);
  int* next_t = (int*)alloc(kNT * 4);
  int* part_m = (int*)alloc(256 * 4);
  int* part_t = (int*)alloc(256 * 4);
  int* csr_tm = (int*)alloc((size_t)kE * 4);
  int* csr_mt = (int*)alloc((size_t)kE * 4);
  float* h_m = (float*)alloc((size_t)kNM * 64 * 4);

  // Zero the two count arrays (adjacent at the front of ws).
  hipMemsetAsync(d_ws, 0, (size_t)((char*)(cnt_t + kNT) - ws), stream);

  // CSR build: histogram -> exclusive scan -> slot fill.
  hist_kernel<<<1024, 256, 0, stream>>>((const int4*)tm_dst, (const int4*)mt_dst,
                                        cnt_m, cnt_t);
  const int nbm = (kNM + 1023) / 1024, nbt = (kNT + 1023) / 1024;
  scan_blocks_kernel<<<nbm + nbt, 256, 0, stream>>>(cnt_m, cnt_t, part_m, part_t,
                                                    nbm);
  scan_partials_kernel<<<2, 256, 0, stream>>>(part_m, part_t, nbm, nbt);
  add_offsets_kernel<<<(kNM + kNT + 255) / 256, 256, 0, stream>>>(
      cnt_m, cnt_t, part_m, part_t, rp_m, rp_t, next_m, next_t);
  fill_csr_kernel<<<1024, 256, 0, stream>>>(
      (const int4*)tm_src, (const int4*)tm_dst, (const int4*)mt_src,
      (const int4*)mt_dst, next_m, next_t, csr_tm, csr_mt);

  // Layer 1, merchants: mean over tm edges (x_trans rows) + x_merch self.
  fused_sage_kernel<128, 64, false><<<640, 512, 0, stream>>>(
      x_trans, x_merch, rp_m, csr_tm, Wl_tm1, bl_tm1, Wr_tm1, h_m, kNM,
      nullptr, nullptr, nullptr);
  // Layer 1, transactions: mean over mt edges (x_merch rows) + x_trans self.
  fused_sage_kernel<64, 128, false><<<1024, 512, 0, stream>>>(
      x_merch, x_trans, rp_t, csr_mt, Wl_mt1, bl_mt1, Wr_mt1, h_t, kNT,
      nullptr, nullptr, nullptr);
  // Layer 2, transactions (+ fused head): mean over mt edges (h_m rows) + h_t.
  fused_sage_kernel<64, 64, true><<<1024, 512, 0, stream>>>(
      h_m, h_t, rp_t, csr_mt, Wl_mt2, bl_mt2, Wr_mt2, h_t, kNT, W_out, b_out,
      out_head);
}